// Round 5
// baseline (71.795 us; speedup 1.0000x reference)
//
#include <hip/hip_runtime.h>

// Problem constants (from reference setup_inputs): B=4, N=4096, D=128.
constexpr int BATCH = 4;
constexpr int N = 4096;
constexpr int D = 128;
constexpr int TILE = 512;            // 512x512 output tile per block
constexpr int NT = N / TILE;         // 8 tile indices per dim

typedef float vfloat4 __attribute__((ext_vector_type(4)));

// dot of one 128-float row with a 128-float weight vector (w uniform -> L1)
__device__ __forceinline__ float dot_row(const float* __restrict__ row,
                                         const float* __restrict__ w) {
    float acc = 0.f;
    #pragma unroll
    for (int c = 0; c < D / 4; ++c) {
        const vfloat4 e  = reinterpret_cast<const vfloat4*>(row)[c];
        const vfloat4 wv = reinterpret_cast<const vfloat4*>(w)[c];
        acc += e.x * wv.x + e.y * wv.y + e.z * wv.z + e.w * wv.w;
    }
    return acc;
}

// ---------------------------------------------------------------------------
// Fused single kernel. Block -> (batch, ti, tj) 512x512 output tile.
// Phase A: 256 threads compute 512 a-dots (rows i0..i0+511) and 512 b-dots
//          (rows j0..j0+511) into LDS. E is 8 MB -> L2/L3-resident, so the
//          redundant panel reads (~128 MB aggregate) are cache-served.
// Phase B: stream the tile. Thread t: fixed float4-cols {t&63, (t&63)+64}
//          (b4 held in regs), rows (t>>6)+4k -> a_lds[row] is wave-uniform
//          (LDS broadcast, free). Stores: 1 KB/wave contiguous, plain
//          (R4 A/B: plain beats nontemporal on gfx950).
// ---------------------------------------------------------------------------
__global__ __launch_bounds__(256)
void fused_kernel(const float* __restrict__ E,
                  const float* __restrict__ W,
                  vfloat4* __restrict__ out) {
    __shared__ float a_lds[TILE];
    __shared__ float b_lds[TILE];

    const int bx    = blockIdx.x;          // 0..255
    const int batch = bx >> 6;             // 4 batches
    const int ti    = (bx >> 3) & (NT - 1);
    const int tj    = bx & (NT - 1);
    const int t     = threadIdx.x;         // 0..255

    const float* Eb = E + (size_t)batch * N * D;
    const float* Wa = W;
    const float* Wb = W + D;

    const int i0 = ti * TILE;
    const int j0 = tj * TILE;

    // Phase A: 4 dots per thread (512 a + 512 b total)
    a_lds[t]       = dot_row(Eb + (size_t)(i0 + t) * D,       Wa);
    a_lds[t + 256] = dot_row(Eb + (size_t)(i0 + t + 256) * D, Wa);
    b_lds[t]       = dot_row(Eb + (size_t)(j0 + t) * D,       Wb);
    b_lds[t + 256] = dot_row(Eb + (size_t)(j0 + t + 256) * D, Wb);
    __syncthreads();

    // Phase B: write the 512x512 tile
    const int j4 = t & 63;                 // float4-col within first 256 cols
    const int r0 = t >> 6;                 // wave id 0..3 (wave-uniform)
    const vfloat4 b4_0 = reinterpret_cast<const vfloat4*>(b_lds)[j4];
    const vfloat4 b4_1 = reinterpret_cast<const vfloat4*>(b_lds)[j4 + 64];

    // out as vfloat4: row stride N/4 = 1024; tile col base = tj*128
    vfloat4* outb = out + ((size_t)batch * N + i0) * (N / 4) + (size_t)tj * (TILE / 4);

    #pragma unroll 4
    for (int k = 0; k < TILE / 4; ++k) {   // 128 iterations, 2 stores each
        const int row = r0 + k * 4;
        const float a = a_lds[row];        // wave-uniform broadcast
        vfloat4* orow = outb + (size_t)row * (N / 4);
        orow[j4]      = b4_0 + a;
        orow[j4 + 64] = b4_1 + a;
    }
}

extern "C" void kernel_launch(void* const* d_in, const int* in_sizes, int n_in,
                              void* d_out, int out_size, void* d_ws, size_t ws_size,
                              hipStream_t stream) {
    const float* E = (const float*)d_in[0];   // (4, 4096, 128) f32
    const float* W = (const float*)d_in[1];   // (1, 256) f32

    // 4 batches x 8x8 tiles = 256 blocks (1 per CU), 256 threads
    fused_kernel<<<BATCH * NT * NT, 256, 0, stream>>>(E, W, (vfloat4*)d_out);
}

// Round 6
// 49.303 us; speedup vs baseline: 1.4562x; 1.4562x over previous
//
#include <hip/hip_runtime.h>

// Problem constants (from reference setup_inputs): B=4, N=4096, D=128.
constexpr int BATCH = 4;
constexpr int N = 4096;
constexpr int D = 128;
constexpr int J4 = N / 4;             // 1024 float4s per output row
constexpr int ROWS_PER_BLOCK = 8;     // rows of out per block (share one batch)

typedef float vfloat4 __attribute__((ext_vector_type(4)));

__device__ __forceinline__ float dot4(const vfloat4 a, const vfloat4 b) {
    return a.x * b.x + a.y * b.y + a.z * b.z + a.w * b.w;
}

// ---------------------------------------------------------------------------
// Kernel 1: per-row dual dot products, v3 (ILP + shorter reduce).
// Wave handles 4 rows via 16-lane groups: g = (tid>>4)&3, s = tid&15.
// Lane loads TWO independent float4s covering bytes [0,256) and [256,512)
// of row (wave*4+g) -> both loads fully coalesced within the 16-lane group,
// 2 loads in flight per lane. Butterfly reduce over 16 lanes (4 steps).
// ---------------------------------------------------------------------------
__global__ __launch_bounds__(256)
void dots_kernel(const float* __restrict__ E,
                 const float* __restrict__ W,
                 float* __restrict__ A,
                 float* __restrict__ Bv) {
    const int gtid = blockIdx.x * blockDim.x + threadIdx.x;
    const int wave = gtid >> 6;          // 0..4095
    const int g    = (threadIdx.x >> 4) & 3;
    const int s    = threadIdx.x & 15;
    const int row  = wave * 4 + g;       // exact fit: 4096*4 = 16384 rows

    const float* rp = E + (size_t)row * D;
    const vfloat4 e1 = *reinterpret_cast<const vfloat4*>(rp + s * 4);        // floats [s*4, s*4+4)
    const vfloat4 e2 = *reinterpret_cast<const vfloat4*>(rp + 64 + s * 4);   // floats [64+s*4, ...)

    const vfloat4 wi1 = *reinterpret_cast<const vfloat4*>(W + s * 4);
    const vfloat4 wi2 = *reinterpret_cast<const vfloat4*>(W + 64 + s * 4);
    const vfloat4 wj1 = *reinterpret_cast<const vfloat4*>(W + D + s * 4);
    const vfloat4 wj2 = *reinterpret_cast<const vfloat4*>(W + D + 64 + s * 4);

    float pa = dot4(e1, wi1) + dot4(e2, wi2);
    float pb = dot4(e1, wj1) + dot4(e2, wj2);

    // reduce across the 16-lane group (xor offsets 8..1 stay in-group)
    #pragma unroll
    for (int off = 8; off >= 1; off >>= 1) {
        pa += __shfl_xor(pa, off);
        pb += __shfl_xor(pb, off);
    }
    if (s == 0) {
        A[row]  = pa;
        Bv[row] = pb;
    }
}

// ---------------------------------------------------------------------------
// Kernel 2: outer-sum materialization (write-bound, 268 MB). UNCHANGED (R4).
//   out[row][j] = A[row] + Bv[(row>>12)*N + j]
// 8 rows/block: a[] hoisted scalar loads, each Bv float4 reused 8x,
// plain stores (R4 A/B: plain beats nontemporal on gfx950).
// ---------------------------------------------------------------------------
__global__ void outer_kernel(const float* __restrict__ A,
                             const float* __restrict__ Bv,
                             vfloat4* __restrict__ out) {
    const int row0  = blockIdx.x * ROWS_PER_BLOCK;
    const int batch = row0 >> 12;                       // row / 4096
    const vfloat4* __restrict__ bv4 =
        reinterpret_cast<const vfloat4*>(Bv) + (size_t)batch * J4;

    float a[ROWS_PER_BLOCK];
    #pragma unroll
    for (int r = 0; r < ROWS_PER_BLOCK; ++r) a[r] = A[row0 + r];

    #pragma unroll
    for (int k = 0; k < J4 / 256; ++k) {                // 4 iterations
        const int j4 = threadIdx.x + k * 256;
        const vfloat4 b4 = bv4[j4];
        #pragma unroll
        for (int r = 0; r < ROWS_PER_BLOCK; ++r) {
            out[(size_t)(row0 + r) * J4 + j4] = b4 + a[r];
        }
    }
}

extern "C" void kernel_launch(void* const* d_in, const int* in_sizes, int n_in,
                              void* d_out, int out_size, void* d_ws, size_t ws_size,
                              hipStream_t stream) {
    const float* E = (const float*)d_in[0];   // (4, 4096, 128) f32
    const float* W = (const float*)d_in[1];   // (1, 256) f32

    // workspace: A (16384 f32) then Bv (16384 f32) = 128 KB
    float* A  = (float*)d_ws;
    float* Bv = A + (size_t)BATCH * N;

    // Kernel 1: 16384 rows, 4 rows/wave, 16 rows/block -> 1024 blocks
    {
        const int threads = 256;
        const int blocks = (BATCH * N) / 16;   // 1024
        dots_kernel<<<blocks, threads, 0, stream>>>(E, W, A, Bv);
    }

    // Kernel 2: 16384 rows / 8 rows-per-block = 2048 blocks
    {
        const int threads = 256;
        const int blocks = (BATCH * N) / ROWS_PER_BLOCK;   // 2048
        outer_kernel<<<blocks, threads, 0, stream>>>(A, Bv, (vfloat4*)d_out);
    }
}